// Round 1
// baseline (2571.741 us; speedup 1.0000x reference)
//
#include <hip/hip_runtime.h>

#define N_NODES 100000
#define N_EDGES 3200000
#define NFEAT 512
#define NHID 256
#define NCLASS 64
#define KHOPS 10

// ---------------- preprocessing: degrees, dinv, CSR ----------------

__global__ __launch_bounds__(256) void zero_deg_kernel(int* __restrict__ deg) {
    int i = blockIdx.x * 256 + threadIdx.x;
    if (i < N_NODES) deg[i] = 0;
}

__global__ __launch_bounds__(256) void deg_kernel(const int* __restrict__ ei, int* __restrict__ deg) {
    int e = blockIdx.x * 256 + threadIdx.x;
    if (e < N_EDGES) atomicAdd(&deg[ei[N_EDGES + e]], 1);
}

__global__ __launch_bounds__(256) void dinv_kernel(const int* __restrict__ deg, float* __restrict__ dinv) {
    int i = blockIdx.x * 256 + threadIdx.x;
    if (i < N_NODES) dinv[i] = rsqrtf((float)(deg[i] + 1)); // +1 self-loop; deg>=1 always
}

// single-block exclusive scan of (deg[i]+1) -> row_ptr, cursor
__global__ __launch_bounds__(1024) void scan_kernel(const int* __restrict__ deg,
                                                    int* __restrict__ row_ptr,
                                                    int* __restrict__ cursor) {
    __shared__ int sums[1024];
    const int CH = (N_NODES + 1023) / 1024; // 98
    int t = threadIdx.x;
    int base = t * CH;
    int s = 0;
    for (int i = 0; i < CH; ++i) {
        int idx = base + i;
        if (idx < N_NODES) s += deg[idx] + 1;
    }
    sums[t] = s;
    __syncthreads();
    for (int off = 1; off < 1024; off <<= 1) {
        int add = (t >= off) ? sums[t - off] : 0;
        __syncthreads();
        sums[t] += add;
        __syncthreads();
    }
    int run = (t == 0) ? 0 : sums[t - 1];
    for (int i = 0; i < CH; ++i) {
        int idx = base + i;
        if (idx < N_NODES) {
            row_ptr[idx] = run;
            cursor[idx]  = run;
            run += deg[idx] + 1;
        }
    }
    if (t == 1023) row_ptr[N_NODES] = sums[1023];
}

__global__ __launch_bounds__(256) void fill_kernel(const int* __restrict__ ei,
                                                   const float* __restrict__ dinv,
                                                   int* __restrict__ cursor,
                                                   int* __restrict__ col,
                                                   float* __restrict__ wgt) {
    int e = blockIdx.x * 256 + threadIdx.x;
    if (e < N_EDGES) {
        int s = ei[e], d = ei[N_EDGES + e];
        int p = atomicAdd(&cursor[d], 1);
        col[p] = s;
        wgt[p] = dinv[s] * dinv[d];
    } else if (e < N_EDGES + N_NODES) {
        int i = e - N_EDGES;
        int p = atomicAdd(&cursor[i], 1);
        col[p] = i;
        wgt[p] = dinv[i] * dinv[i]; // self-loop
    }
}

// ---------------- fused MLP: h = relu(x@W1+b1)@W2+b2 ; hidden = temp0*h ----------------
// block = 256 threads, 16 rows per block. Stage 1: thread tile 4 rows x 4 cols of [16,256].
// W1 chunk staged in LDS (16 k-slices). Stage 2 uses h1 in LDS.

__global__ __launch_bounds__(256) void mlp_kernel(const float* __restrict__ x,
                                                  const float* __restrict__ W1,
                                                  const float* __restrict__ b1,
                                                  const float* __restrict__ W2,
                                                  const float* __restrict__ b2,
                                                  const float* __restrict__ temp,
                                                  float* __restrict__ h,
                                                  float* __restrict__ hidden) {
    __shared__ float xs[16 * 516];   // x tile, padded row pitch (516 keeps 16B align)
    __shared__ float wsb[16 * 260];  // W1 chunk view [16][256], then h1 view [16][260]

    int t = threadIdx.x;
    int lane = t & 63;
    int rt = t >> 6;
    int rbase = rt * 4;
    int row0 = blockIdx.x * 16;

    // load x tile (rows contiguous -> one flat coalesced float4 copy, row-repacked)
    const float4* xsrc = (const float4*)(x + (size_t)row0 * NFEAT);
    for (int i = t; i < 16 * 128; i += 256) {
        int r = i >> 7, c4 = i & 127;
        float4 v = xsrc[i];
        *(float4*)&xs[r * 516 + c4 * 4] = v;
    }

    float acc[4][4] = {};
    for (int kc = 0; kc < NFEAT; kc += 16) {
        __syncthreads(); // protect previous chunk reads / xs load
        const float4* wsrc = (const float4*)(W1 + (size_t)kc * NHID);
        for (int i = t; i < 16 * 64; i += 256) ((float4*)wsb)[i] = wsrc[i];
        __syncthreads();
        #pragma unroll
        for (int k4 = 0; k4 < 16; k4 += 4) {
            float4 xr[4];
            #pragma unroll
            for (int r = 0; r < 4; ++r)
                xr[r] = *(const float4*)&xs[(rbase + r) * 516 + kc + k4];
            #pragma unroll
            for (int kk = 0; kk < 4; ++kk) {
                float4 wv = *(const float4*)&wsb[(k4 + kk) * 256 + lane * 4];
                #pragma unroll
                for (int r = 0; r < 4; ++r) {
                    float xv = ((const float*)&xr[r])[kk];
                    acc[r][0] = fmaf(xv, wv.x, acc[r][0]);
                    acc[r][1] = fmaf(xv, wv.y, acc[r][1]);
                    acc[r][2] = fmaf(xv, wv.z, acc[r][2]);
                    acc[r][3] = fmaf(xv, wv.w, acc[r][3]);
                }
            }
        }
    }
    __syncthreads(); // all W1-chunk reads done before overwriting wsb with h1

    // bias + relu -> h1 in LDS, [16][260]
    float4 bv = *(const float4*)&b1[lane * 4];
    #pragma unroll
    for (int r = 0; r < 4; ++r) {
        float4 o;
        o.x = fmaxf(acc[r][0] + bv.x, 0.f);
        o.y = fmaxf(acc[r][1] + bv.y, 0.f);
        o.z = fmaxf(acc[r][2] + bv.z, 0.f);
        o.w = fmaxf(acc[r][3] + bv.w, 0.f);
        *(float4*)&wsb[(rbase + r) * 260 + lane * 4] = o;
    }
    __syncthreads();

    // stage 2: thread = (col lane, rows rbase..rbase+3), K=256
    float acc2[4] = {0.f, 0.f, 0.f, 0.f};
    for (int k = 0; k < NHID; k += 4) {
        float4 hv[4];
        #pragma unroll
        for (int r = 0; r < 4; ++r)
            hv[r] = *(const float4*)&wsb[(rbase + r) * 260 + k];
        #pragma unroll
        for (int kk = 0; kk < 4; ++kk) {
            float w2 = W2[(k + kk) * NCLASS + lane];
            #pragma unroll
            for (int r = 0; r < 4; ++r)
                acc2[r] = fmaf(((const float*)&hv[r])[kk], w2, acc2[r]);
        }
    }
    float t0 = temp[0];
    float bb = b2[lane];
    #pragma unroll
    for (int r = 0; r < 4; ++r) {
        float v = acc2[r] + bb;
        size_t idx = (size_t)(row0 + rbase + r) * NCLASS + lane;
        h[idx] = v;
        hidden[idx] = t0 * v;
    }
}

// ---------------- propagation: one wave per dst node, pull over CSR ----------------

__global__ __launch_bounds__(64) void prop_kernel(const float* __restrict__ hin,
                                                  float* __restrict__ hout,
                                                  float* __restrict__ hidden,
                                                  const int* __restrict__ row_ptr,
                                                  const int* __restrict__ col,
                                                  const float* __restrict__ wgt,
                                                  const float* __restrict__ temp,
                                                  int ktap) {
    int i = blockIdx.x;
    int j = threadIdx.x;
    int beg = row_ptr[i], end = row_ptr[i + 1];
    float acc = 0.f;
    int e = beg;
    for (; e + 4 <= end; e += 4) {
        int s0 = col[e], s1 = col[e + 1], s2 = col[e + 2], s3 = col[e + 3];
        float w0 = wgt[e], w1 = wgt[e + 1], w2 = wgt[e + 2], w3 = wgt[e + 3];
        float v0 = hin[s0 * 64 + j];
        float v1 = hin[s1 * 64 + j];
        float v2 = hin[s2 * 64 + j];
        float v3 = hin[s3 * 64 + j];
        acc = fmaf(w0, v0, acc);
        acc = fmaf(w1, v1, acc);
        acc = fmaf(w2, v2, acc);
        acc = fmaf(w3, v3, acc);
    }
    for (; e < end; ++e) acc = fmaf(wgt[e], hin[col[e] * 64 + j], acc);
    float tk = temp[ktap];
    hout[i * 64 + j] = acc;
    hidden[i * 64 + j] = fmaf(tk, acc, hidden[i * 64 + j]);
}

// ---------------- log_softmax in-place on d_out ----------------

__global__ __launch_bounds__(64) void lsm_kernel(float* __restrict__ io) {
    int i = blockIdx.x, j = threadIdx.x;
    float v = io[i * 64 + j];
    float m = v;
    #pragma unroll
    for (int o = 32; o > 0; o >>= 1) m = fmaxf(m, __shfl_xor(m, o));
    float ex = expf(v - m);
    float s = ex;
    #pragma unroll
    for (int o = 32; o > 0; o >>= 1) s += __shfl_xor(s, o);
    io[i * 64 + j] = v - m - logf(s);
}

extern "C" void kernel_launch(void* const* d_in, const int* in_sizes, int n_in,
                              void* d_out, int out_size, void* d_ws, size_t ws_size,
                              hipStream_t stream) {
    const float* x    = (const float*)d_in[0];
    const int*   ei   = (const int*)d_in[1];
    const float* W1   = (const float*)d_in[2];
    const float* b1   = (const float*)d_in[3];
    const float* W2   = (const float*)d_in[4];
    const float* b2   = (const float*)d_in[5];
    const float* temp = (const float*)d_in[6];
    float* out = (float*)d_out;

    char* ws = (char*)d_ws;
    size_t off = 0;
    auto alloc = [&](size_t bytes) -> void* {
        void* p = ws + off;
        off = (off + bytes + 255) & ~(size_t)255;
        return p;
    };
    int*   deg     = (int*)alloc((size_t)N_NODES * 4);
    float* dinv    = (float*)alloc((size_t)N_NODES * 4);
    int*   row_ptr = (int*)alloc((size_t)(N_NODES + 1) * 4);
    int*   cursor  = (int*)alloc((size_t)N_NODES * 4);
    int*   colb    = (int*)alloc((size_t)(N_EDGES + N_NODES) * 4);
    float* wgtb    = (float*)alloc((size_t)(N_EDGES + N_NODES) * 4);
    float* h0      = (float*)alloc((size_t)N_NODES * NCLASS * 4);
    float* h1      = (float*)alloc((size_t)N_NODES * NCLASS * 4);
    float* hidden  = out; // accumulate GPR combination directly in d_out

    zero_deg_kernel<<<(N_NODES + 255) / 256, 256, 0, stream>>>(deg);
    deg_kernel<<<(N_EDGES + 255) / 256, 256, 0, stream>>>(ei, deg);
    dinv_kernel<<<(N_NODES + 255) / 256, 256, 0, stream>>>(deg, dinv);
    scan_kernel<<<1, 1024, 0, stream>>>(deg, row_ptr, cursor);
    fill_kernel<<<(N_EDGES + N_NODES + 255) / 256, 256, 0, stream>>>(ei, dinv, cursor, colb, wgtb);

    mlp_kernel<<<N_NODES / 16, 256, 0, stream>>>(x, W1, b1, W2, b2, temp, h0, hidden);

    float* cur = h0;
    float* nxt = h1;
    for (int k = 0; k < KHOPS; ++k) {
        prop_kernel<<<N_NODES, 64, 0, stream>>>(cur, nxt, hidden, row_ptr, colb, wgtb, temp, k + 1);
        float* tswap = cur; cur = nxt; nxt = tswap;
    }

    lsm_kernel<<<N_NODES, 64, 0, stream>>>(hidden);
}

// Round 2
// 2116.514 us; speedup vs baseline: 1.2151x; 1.2151x over previous
//
#include <hip/hip_runtime.h>

#define N_NODES 100000
#define N_EDGES 3200000
#define NFEAT 512
#define NHID 256
#define NCLASS 64
#define KHOPS 10

typedef __bf16 bf16x8 __attribute__((ext_vector_type(8)));
typedef __bf16 bf16x4 __attribute__((ext_vector_type(4)));
typedef float f32x4 __attribute__((ext_vector_type(4)));

// ---------------- preprocessing: degrees, dinv, CSR ----------------

__global__ __launch_bounds__(256) void zero_deg_kernel(int* __restrict__ deg) {
    int i = blockIdx.x * 256 + threadIdx.x;
    if (i < N_NODES) deg[i] = 0;
}

__global__ __launch_bounds__(256) void deg_kernel(const int* __restrict__ ei, int* __restrict__ deg) {
    int e = blockIdx.x * 256 + threadIdx.x;
    if (e < N_EDGES) atomicAdd(&deg[ei[N_EDGES + e]], 1);
}

__global__ __launch_bounds__(256) void dinv_kernel(const int* __restrict__ deg, float* __restrict__ dinv) {
    int i = blockIdx.x * 256 + threadIdx.x;
    if (i < N_NODES) dinv[i] = rsqrtf((float)(deg[i] + 1)); // +1 self-loop
}

// single-block exclusive scan of (deg[i]+1) -> row_ptr, cursor
__global__ __launch_bounds__(1024) void scan_kernel(const int* __restrict__ deg,
                                                    int* __restrict__ row_ptr,
                                                    int* __restrict__ cursor) {
    __shared__ int sums[1024];
    const int CH = (N_NODES + 1023) / 1024; // 98
    int t = threadIdx.x;
    int base = t * CH;
    int s = 0;
    for (int i = 0; i < CH; ++i) {
        int idx = base + i;
        if (idx < N_NODES) s += deg[idx] + 1;
    }
    sums[t] = s;
    __syncthreads();
    for (int off = 1; off < 1024; off <<= 1) {
        int add = (t >= off) ? sums[t - off] : 0;
        __syncthreads();
        sums[t] += add;
        __syncthreads();
    }
    int run = (t == 0) ? 0 : sums[t - 1];
    for (int i = 0; i < CH; ++i) {
        int idx = base + i;
        if (idx < N_NODES) {
            row_ptr[idx] = run;
            cursor[idx]  = run;
            run += deg[idx] + 1;
        }
    }
    if (t == 1023) row_ptr[N_NODES] = sums[1023];
}

__global__ __launch_bounds__(256) void fill_kernel(const int* __restrict__ ei,
                                                   const float* __restrict__ dinv,
                                                   int* __restrict__ cursor,
                                                   int* __restrict__ col,
                                                   float* __restrict__ wgt) {
    int e = blockIdx.x * 256 + threadIdx.x;
    if (e < N_EDGES) {
        int s = ei[e], d = ei[N_EDGES + e];
        int p = atomicAdd(&cursor[d], 1);
        col[p] = s;
        wgt[p] = dinv[s] * dinv[d];
    } else if (e < N_EDGES + N_NODES) {
        int i = e - N_EDGES;
        int p = atomicAdd(&cursor[i], 1);
        col[p] = i;
        wgt[p] = dinv[i] * dinv[i]; // self-loop
    }
}

// ---------------- weight prep: W1^T, W2^T in bf16 ----------------

__global__ __launch_bounds__(256) void wprep_kernel(const float* __restrict__ W1,
                                                    const float* __restrict__ W2,
                                                    __bf16* __restrict__ w1t,
                                                    __bf16* __restrict__ w2t) {
    int i = blockIdx.x * 256 + threadIdx.x;
    if (i < NFEAT * NHID) {
        int n = i >> 9, k = i & 511;           // w1t[n][k], k<512
        w1t[i] = (__bf16)W1[k * NHID + n];
    } else {
        int j = i - NFEAT * NHID;
        if (j < NHID * NCLASS) {
            int n = j >> 8, k = j & 255;       // w2t[n][k], k<256
            w2t[j] = (__bf16)W2[k * NCLASS + n];
        }
    }
}

// ---------------- fused MLP via bf16 MFMA ----------------
// block = 256 (4 waves), 64-row tile. Layer1: wave w -> n in [64w,64w+64), all 64 rows,
// acc 4x4 tiles of 16x16x32. Layer2: wave w -> rows [16w,16w+16), N=64, K=256 from LDS h1.

#define MT 64
#define KC 64
#define XP 72    // xs pitch (bf16 elems): 144B/row -> rows offset 4 banks -> 2-way (free)
#define WP 72
#define HP 264   // h1 pitch: 528B/row -> 4-bank offset

__global__ __launch_bounds__(256) void mlp_kernel(const float* __restrict__ x,
                                                  const __bf16* __restrict__ w1t,
                                                  const float* __restrict__ b1,
                                                  const __bf16* __restrict__ w2t,
                                                  const float* __restrict__ b2,
                                                  const float* __restrict__ temp,
                                                  float* __restrict__ h,
                                                  float* __restrict__ hidden) {
    __shared__ char smem[46080] __attribute__((aligned(16)));
    __bf16* xs  = (__bf16*)smem;             // 64*72*2  = 9216 B
    __bf16* wt  = (__bf16*)(smem + 9216);    // 256*72*2 = 36864 B
    __bf16* h1s = (__bf16*)smem;             // 64*264*2 = 33792 B (after barrier)

    int t = threadIdx.x;
    int wv = t >> 6, lane = t & 63;
    int lrow = lane & 15;        // fragment row/col index
    int quad = lane >> 4;        // k-group
    int row0 = blockIdx.x * MT;
    int n0 = wv * 64;

    f32x4 acc[4][4] = {};
    for (int kc = 0; kc < NFEAT; kc += KC) {
        __syncthreads();
        // stage x tile (fp32 -> bf16): 64 rows x 16 float4
        for (int i = t; i < MT * 16; i += 256) {
            int r = i >> 4, c4 = i & 15;
            int row = row0 + r; if (row >= N_NODES) row = N_NODES - 1;
            float4 v = *(const float4*)&x[(size_t)row * NFEAT + kc + c4 * 4];
            bf16x4 o = { (__bf16)v.x, (__bf16)v.y, (__bf16)v.z, (__bf16)v.w };
            *(bf16x4*)&xs[r * XP + c4 * 4] = o;
        }
        // stage W1^T chunk: 256 n x 8 groups of 8 bf16
        for (int i = t; i < 256 * 8; i += 256) {
            int n = i >> 3, c8 = i & 7;
            bf16x8 v = *(const bf16x8*)&w1t[(size_t)n * NFEAT + kc + c8 * 8];
            *(bf16x8*)&wt[n * WP + c8 * 8] = v;
        }
        __syncthreads();
        #pragma unroll
        for (int ks = 0; ks < 2; ++ks) {
            int kof = ks * 32 + quad * 8;
            bf16x8 a[4], b[4];
            #pragma unroll
            for (int mt = 0; mt < 4; ++mt)
                a[mt] = *(const bf16x8*)&xs[(mt * 16 + lrow) * XP + kof];
            #pragma unroll
            for (int nt = 0; nt < 4; ++nt)
                b[nt] = *(const bf16x8*)&wt[(n0 + nt * 16 + lrow) * WP + kof];
            #pragma unroll
            for (int mt = 0; mt < 4; ++mt)
                #pragma unroll
                for (int nt = 0; nt < 4; ++nt)
                    acc[mt][nt] = __builtin_amdgcn_mfma_f32_16x16x32_bf16(a[mt], b[nt], acc[mt][nt], 0, 0, 0);
        }
    }
    __syncthreads();
    // epilogue 1: bias + relu -> h1s (bf16). C/D layout: col=lane&15, row=quad*4+reg
    #pragma unroll
    for (int nt = 0; nt < 4; ++nt) {
        int coln = n0 + nt * 16 + lrow;
        float bb = b1[coln];
        #pragma unroll
        for (int mt = 0; mt < 4; ++mt) {
            int rbase = mt * 16 + quad * 4;
            #pragma unroll
            for (int r = 0; r < 4; ++r) {
                float v = acc[mt][nt][r] + bb;
                h1s[(rbase + r) * HP + coln] = (__bf16)fmaxf(v, 0.f);
            }
        }
    }
    __syncthreads();
    // layer 2: rows [16*wv, 16*wv+16), K=256, N=64 (B straight from global w2t, L1-hot)
    f32x4 acc2[4] = {};
    #pragma unroll
    for (int ks = 0; ks < 8; ++ks) {
        int kof = ks * 32 + quad * 8;
        bf16x8 a2 = *(const bf16x8*)&h1s[(wv * 16 + lrow) * HP + kof];
        #pragma unroll
        for (int nt = 0; nt < 4; ++nt) {
            bf16x8 bv = *(const bf16x8*)&w2t[(size_t)(nt * 16 + lrow) * NHID + kof];
            acc2[nt] = __builtin_amdgcn_mfma_f32_16x16x32_bf16(a2, bv, acc2[nt], 0, 0, 0);
        }
    }
    float t0 = temp[0];
    #pragma unroll
    for (int nt = 0; nt < 4; ++nt) {
        int coln = nt * 16 + lrow;
        float bb = b2[coln];
        #pragma unroll
        for (int r = 0; r < 4; ++r) {
            int row = row0 + wv * 16 + quad * 4 + r;
            if (row < N_NODES) {
                float v = acc2[nt][r] + bb;
                size_t idx = (size_t)row * NCLASS + coln;
                h[idx] = v;
                hidden[idx] = t0 * v;
            }
        }
    }
}

// ---------------- propagation: wave per dst node, 4 nodes/block ----------------
// col/wgt loaded coalesced once per 64 edges into lanes, broadcast via v_readlane;
// 8 independent gathers in flight per wave.

__global__ __launch_bounds__(256) void prop_kernel(const float* __restrict__ hin,
                                                   float* __restrict__ hout,
                                                   float* __restrict__ hidden,
                                                   const int* __restrict__ row_ptr,
                                                   const int* __restrict__ col,
                                                   const float* __restrict__ wgt,
                                                   const float* __restrict__ temp,
                                                   int ktap) {
    int node = blockIdx.x * 4 + (threadIdx.x >> 6);
    int lane = threadIdx.x & 63;
    int beg = row_ptr[node], end = row_ptr[node + 1];
    float acc = 0.f;
    for (int base = beg; base < end; base += 64) {
        int e = base + lane;
        int c = 0; float w = 0.f;
        if (e < end) { c = col[e]; w = wgt[e]; }
        int cnt = end - base; if (cnt > 64) cnt = 64;
        int tt = 0;
        for (; tt + 8 <= cnt; tt += 8) {
            #pragma unroll
            for (int u = 0; u < 8; ++u) {
                int s  = __builtin_amdgcn_readlane(c, tt + u);
                int wi = __builtin_amdgcn_readlane(__float_as_int(w), tt + u);
                acc = fmaf(__int_as_float(wi), hin[(size_t)s * 64 + lane], acc);
            }
        }
        for (; tt < cnt; ++tt) {
            int s  = __builtin_amdgcn_readlane(c, tt);
            int wi = __builtin_amdgcn_readlane(__float_as_int(w), tt);
            acc = fmaf(__int_as_float(wi), hin[(size_t)s * 64 + lane], acc);
        }
    }
    float tk = temp[ktap];
    size_t idx = (size_t)node * 64 + lane;
    hout[idx] = acc;
    hidden[idx] = fmaf(tk, acc, hidden[idx]);
}

// ---------------- log_softmax in-place on d_out ----------------

__global__ __launch_bounds__(256) void lsm_kernel(float* __restrict__ io) {
    int i = blockIdx.x * 4 + (threadIdx.x >> 6);
    int j = threadIdx.x & 63;
    float v = io[(size_t)i * 64 + j];
    float m = v;
    #pragma unroll
    for (int o = 32; o > 0; o >>= 1) m = fmaxf(m, __shfl_xor(m, o));
    float ex = expf(v - m);
    float s = ex;
    #pragma unroll
    for (int o = 32; o > 0; o >>= 1) s += __shfl_xor(s, o);
    io[(size_t)i * 64 + j] = v - m - logf(s);
}

extern "C" void kernel_launch(void* const* d_in, const int* in_sizes, int n_in,
                              void* d_out, int out_size, void* d_ws, size_t ws_size,
                              hipStream_t stream) {
    const float* x    = (const float*)d_in[0];
    const int*   ei   = (const int*)d_in[1];
    const float* W1   = (const float*)d_in[2];
    const float* b1   = (const float*)d_in[3];
    const float* W2   = (const float*)d_in[4];
    const float* b2   = (const float*)d_in[5];
    const float* temp = (const float*)d_in[6];
    float* out = (float*)d_out;

    char* ws = (char*)d_ws;
    size_t off = 0;
    auto alloc = [&](size_t bytes) -> void* {
        void* p = ws + off;
        off = (off + bytes + 255) & ~(size_t)255;
        return p;
    };
    int*    deg     = (int*)alloc((size_t)N_NODES * 4);
    float*  dinv    = (float*)alloc((size_t)N_NODES * 4);
    int*    row_ptr = (int*)alloc((size_t)(N_NODES + 1) * 4);
    int*    cursor  = (int*)alloc((size_t)N_NODES * 4);
    int*    colb    = (int*)alloc((size_t)(N_EDGES + N_NODES) * 4);
    float*  wgtb    = (float*)alloc((size_t)(N_EDGES + N_NODES) * 4);
    float*  h0      = (float*)alloc((size_t)N_NODES * NCLASS * 4);
    float*  h1      = (float*)alloc((size_t)N_NODES * NCLASS * 4);
    __bf16* w1t     = (__bf16*)alloc((size_t)NFEAT * NHID * 2);
    __bf16* w2t     = (__bf16*)alloc((size_t)NHID * NCLASS * 2);
    float*  hidden  = out; // accumulate GPR combination directly in d_out

    zero_deg_kernel<<<(N_NODES + 255) / 256, 256, 0, stream>>>(deg);
    deg_kernel<<<(N_EDGES + 255) / 256, 256, 0, stream>>>(ei, deg);
    dinv_kernel<<<(N_NODES + 255) / 256, 256, 0, stream>>>(deg, dinv);
    scan_kernel<<<1, 1024, 0, stream>>>(deg, row_ptr, cursor);
    fill_kernel<<<(N_EDGES + N_NODES + 255) / 256, 256, 0, stream>>>(ei, dinv, cursor, colb, wgtb);
    wprep_kernel<<<(NFEAT * NHID + NHID * NCLASS + 255) / 256, 256, 0, stream>>>(W1, W2, w1t, w2t);

    mlp_kernel<<<(N_NODES + MT - 1) / MT, 256, 0, stream>>>(x, w1t, b1, w2t, b2, temp, h0, out);

    float* cur = h0;
    float* nxt = h1;
    for (int k = 0; k < KHOPS; ++k) {
        prop_kernel<<<N_NODES / 4, 256, 0, stream>>>(cur, nxt, out, row_ptr, colb, wgtb, temp, k + 1);
        float* tswap = cur; cur = nxt; nxt = tswap;
    }

    lsm_kernel<<<N_NODES / 4, 256, 0, stream>>>(out);
}

// Round 3
// 1482.856 us; speedup vs baseline: 1.7343x; 1.4273x over previous
//
#include <hip/hip_runtime.h>

#define N_NODES 100000
#define N_EDGES 3200000
#define NFEAT 512
#define NHID 256
#define NCLASS 64
#define KHOPS 10
#define SCAN_B 391   // ceil(N_NODES/256)

typedef __bf16 bf16x8 __attribute__((ext_vector_type(8)));
typedef __bf16 bf16x4 __attribute__((ext_vector_type(4)));
typedef float f32x4 __attribute__((ext_vector_type(4)));

// ---------------- preprocessing: degrees, dinv, CSR ----------------

__global__ __launch_bounds__(256) void zero_deg_kernel(int* __restrict__ deg) {
    int i = blockIdx.x * 256 + threadIdx.x;
    if (i < N_NODES) deg[i] = 0;
}

__global__ __launch_bounds__(256) void deg_kernel(const int* __restrict__ ei, int* __restrict__ deg) {
    int e = blockIdx.x * 256 + threadIdx.x;
    if (e < N_EDGES) atomicAdd(&deg[ei[N_EDGES + e]], 1);
}

__global__ __launch_bounds__(256) void dinv_kernel(const int* __restrict__ deg, float* __restrict__ dinv) {
    int i = blockIdx.x * 256 + threadIdx.x;
    if (i < N_NODES) dinv[i] = rsqrtf((float)(deg[i] + 1)); // +1 self-loop
}

// ---- hierarchical scan of (deg[i]+1): partial sums -> scan partials -> local scan ----

__global__ __launch_bounds__(256) void scan1_kernel(const int* __restrict__ deg, int* __restrict__ partial) {
    __shared__ int red[256];
    int t = threadIdx.x;
    int i = blockIdx.x * 256 + t;
    red[t] = (i < N_NODES) ? deg[i] + 1 : 0;
    __syncthreads();
    for (int off = 128; off > 0; off >>= 1) {
        if (t < off) red[t] += red[t + off];
        __syncthreads();
    }
    if (t == 0) partial[blockIdx.x] = red[0];
}

__global__ __launch_bounds__(512) void scan2_kernel(int* __restrict__ partial) {
    __shared__ int s[512];
    int t = threadIdx.x;
    int v = (t < SCAN_B) ? partial[t] : 0;
    s[t] = v;
    __syncthreads();
    for (int off = 1; off < 512; off <<= 1) {
        int add = (t >= off) ? s[t - off] : 0;
        __syncthreads();
        s[t] += add;
        __syncthreads();
    }
    if (t < SCAN_B) partial[t] = s[t] - v; // exclusive
}

__global__ __launch_bounds__(256) void scan3_kernel(const int* __restrict__ deg,
                                                    const int* __restrict__ partial,
                                                    int* __restrict__ row_ptr,
                                                    int* __restrict__ cursor) {
    __shared__ int s[256];
    int t = threadIdx.x;
    int i = blockIdx.x * 256 + t;
    int v = (i < N_NODES) ? deg[i] + 1 : 0;
    s[t] = v;
    __syncthreads();
    for (int off = 1; off < 256; off <<= 1) {
        int add = (t >= off) ? s[t - off] : 0;
        __syncthreads();
        s[t] += add;
        __syncthreads();
    }
    int excl = s[t] - v + partial[blockIdx.x];
    if (i < N_NODES) {
        row_ptr[i] = excl;
        cursor[i] = excl;
        if (i == N_NODES - 1) row_ptr[N_NODES] = excl + v;
    }
}

__global__ __launch_bounds__(256) void fill_kernel(const int* __restrict__ ei,
                                                   const float* __restrict__ dinv,
                                                   int* __restrict__ cursor,
                                                   int* __restrict__ col,
                                                   float* __restrict__ wgt) {
    int e = blockIdx.x * 256 + threadIdx.x;
    if (e < N_EDGES) {
        int s = ei[e], d = ei[N_EDGES + e];
        int p = atomicAdd(&cursor[d], 1);
        col[p] = s;
        wgt[p] = dinv[s] * dinv[d];
    } else if (e < N_EDGES + N_NODES) {
        int i = e - N_EDGES;
        int p = atomicAdd(&cursor[i], 1);
        col[p] = i;
        wgt[p] = dinv[i] * dinv[i]; // self-loop
    }
}

// ---------------- weight prep: W1^T, W2^T in bf16 ----------------

__global__ __launch_bounds__(256) void wprep_kernel(const float* __restrict__ W1,
                                                    const float* __restrict__ W2,
                                                    __bf16* __restrict__ w1t,
                                                    __bf16* __restrict__ w2t) {
    int i = blockIdx.x * 256 + threadIdx.x;
    if (i < NFEAT * NHID) {
        int n = i >> 9, k = i & 511;           // w1t[n][k], k<512
        w1t[i] = (__bf16)W1[k * NHID + n];
    } else {
        int j = i - NFEAT * NHID;
        if (j < NHID * NCLASS) {
            int n = j >> 8, k = j & 255;       // w2t[n][k], k<256
            w2t[j] = (__bf16)W2[k * NCLASS + n];
        }
    }
}

// ---------------- fused MLP via bf16 MFMA ----------------

#define MT 64
#define KC 64
#define XP 72
#define WP 72
#define HP 264

__global__ __launch_bounds__(256) void mlp_kernel(const float* __restrict__ x,
                                                  const __bf16* __restrict__ w1t,
                                                  const float* __restrict__ b1,
                                                  const __bf16* __restrict__ w2t,
                                                  const float* __restrict__ b2,
                                                  const float* __restrict__ temp,
                                                  __bf16* __restrict__ h,
                                                  float* __restrict__ hidden) {
    __shared__ char smem[46080] __attribute__((aligned(16)));
    __bf16* xs  = (__bf16*)smem;             // 64*72*2  = 9216 B
    __bf16* wt  = (__bf16*)(smem + 9216);    // 256*72*2 = 36864 B
    __bf16* h1s = (__bf16*)smem;             // 64*264*2 = 33792 B (after barrier)

    int t = threadIdx.x;
    int wv = t >> 6, lane = t & 63;
    int lrow = lane & 15;
    int quad = lane >> 4;
    int row0 = blockIdx.x * MT;
    int n0 = wv * 64;

    f32x4 acc[4][4] = {};
    for (int kc = 0; kc < NFEAT; kc += KC) {
        __syncthreads();
        for (int i = t; i < MT * 16; i += 256) {
            int r = i >> 4, c4 = i & 15;
            int row = row0 + r; if (row >= N_NODES) row = N_NODES - 1;
            float4 v = *(const float4*)&x[(size_t)row * NFEAT + kc + c4 * 4];
            bf16x4 o = { (__bf16)v.x, (__bf16)v.y, (__bf16)v.z, (__bf16)v.w };
            *(bf16x4*)&xs[r * XP + c4 * 4] = o;
        }
        for (int i = t; i < 256 * 8; i += 256) {
            int n = i >> 3, c8 = i & 7;
            bf16x8 v = *(const bf16x8*)&w1t[(size_t)n * NFEAT + kc + c8 * 8];
            *(bf16x8*)&wt[n * WP + c8 * 8] = v;
        }
        __syncthreads();
        #pragma unroll
        for (int ks = 0; ks < 2; ++ks) {
            int kof = ks * 32 + quad * 8;
            bf16x8 a[4], b[4];
            #pragma unroll
            for (int mt = 0; mt < 4; ++mt)
                a[mt] = *(const bf16x8*)&xs[(mt * 16 + lrow) * XP + kof];
            #pragma unroll
            for (int nt = 0; nt < 4; ++nt)
                b[nt] = *(const bf16x8*)&wt[(n0 + nt * 16 + lrow) * WP + kof];
            #pragma unroll
            for (int mt = 0; mt < 4; ++mt)
                #pragma unroll
                for (int nt = 0; nt < 4; ++nt)
                    acc[mt][nt] = __builtin_amdgcn_mfma_f32_16x16x32_bf16(a[mt], b[nt], acc[mt][nt], 0, 0, 0);
        }
    }
    __syncthreads();
    #pragma unroll
    for (int nt = 0; nt < 4; ++nt) {
        int coln = n0 + nt * 16 + lrow;
        float bb = b1[coln];
        #pragma unroll
        for (int mt = 0; mt < 4; ++mt) {
            int rbase = mt * 16 + quad * 4;
            #pragma unroll
            for (int r = 0; r < 4; ++r) {
                float v = acc[mt][nt][r] + bb;
                h1s[(rbase + r) * HP + coln] = (__bf16)fmaxf(v, 0.f);
            }
        }
    }
    __syncthreads();
    f32x4 acc2[4] = {};
    #pragma unroll
    for (int ks = 0; ks < 8; ++ks) {
        int kof = ks * 32 + quad * 8;
        bf16x8 a2 = *(const bf16x8*)&h1s[(wv * 16 + lrow) * HP + kof];
        #pragma unroll
        for (int nt = 0; nt < 4; ++nt) {
            bf16x8 bv = *(const bf16x8*)&w2t[(size_t)(nt * 16 + lrow) * NHID + kof];
            acc2[nt] = __builtin_amdgcn_mfma_f32_16x16x32_bf16(a2, bv, acc2[nt], 0, 0, 0);
        }
    }
    float t0 = temp[0];
    #pragma unroll
    for (int nt = 0; nt < 4; ++nt) {
        int coln = nt * 16 + lrow;
        float bb = b2[coln];
        #pragma unroll
        for (int r = 0; r < 4; ++r) {
            int row = row0 + wv * 16 + quad * 4 + r;
            if (row < N_NODES) {
                float v = acc2[nt][r] + bb;
                size_t idx = (size_t)row * NCLASS + coln;
                h[idx] = (__bf16)v;
                hidden[idx] = t0 * v;
            }
        }
    }
}

// ---------------- propagation: wave per dst node, bf16 h, 2 edges per load ----------------
// lanes 0-31 handle edge e (features 2*fi,2*fi+1), lanes 32-63 edge e+1; combine via shfl_xor(32).

__global__ __launch_bounds__(256) void prop_kernel(const __bf16* __restrict__ hin,
                                                   __bf16* __restrict__ hout,
                                                   float* __restrict__ hidden,
                                                   const int* __restrict__ row_ptr,
                                                   const int* __restrict__ col,
                                                   const float* __restrict__ wgt,
                                                   const float* __restrict__ temp,
                                                   int ktap) {
    int node = blockIdx.x * 4 + (threadIdx.x >> 6);
    int lane = threadIdx.x & 63;
    int half = lane >> 5;
    int fi = lane & 31;
    const unsigned int* hin32 = (const unsigned int*)hin; // [s*32 + fi] = 2 bf16 feats
    int beg = row_ptr[node], end = row_ptr[node + 1];
    float acc0 = 0.f, acc1 = 0.f;
    for (int base = beg; base < end; base += 64) {
        int e = base + lane;
        int c = 0, wi = 0;
        if (e < end) { c = col[e]; wi = __float_as_int(wgt[e]); }
        int cnt = end - base; if (cnt > 64) cnt = 64;
        int tt = 0;
        for (; tt + 16 <= cnt; tt += 16) {
            #pragma unroll
            for (int u = 0; u < 8; ++u) {
                int sA = __builtin_amdgcn_readlane(c, tt + 2 * u);
                int wA = __builtin_amdgcn_readlane(wi, tt + 2 * u);
                int sB = __builtin_amdgcn_readlane(c, tt + 2 * u + 1);
                int wB = __builtin_amdgcn_readlane(wi, tt + 2 * u + 1);
                int s = half ? sB : sA;
                float w = __int_as_float(half ? wB : wA);
                unsigned int v = hin32[(size_t)s * 32 + fi];
                acc0 = fmaf(w, __int_as_float(v << 16), acc0);
                acc1 = fmaf(w, __int_as_float(v & 0xffff0000u), acc1);
            }
        }
        for (; tt < cnt; tt += 2) {
            int sA = __builtin_amdgcn_readlane(c, tt);
            int wA = __builtin_amdgcn_readlane(wi, tt);
            int sB = sA, wB = 0;
            if (tt + 1 < cnt) {
                sB = __builtin_amdgcn_readlane(c, tt + 1);
                wB = __builtin_amdgcn_readlane(wi, tt + 1);
            }
            int s = half ? sB : sA;
            float w = __int_as_float(half ? wB : wA);
            unsigned int v = hin32[(size_t)s * 32 + fi];
            acc0 = fmaf(w, __int_as_float(v << 16), acc0);
            acc1 = fmaf(w, __int_as_float(v & 0xffff0000u), acc1);
        }
    }
    acc0 += __shfl_xor(acc0, 32);
    acc1 += __shfl_xor(acc1, 32);
    float tk = temp[ktap];
    if (half == 0) {
        union { __bf16 hb[2]; unsigned int u; } pk;
        pk.hb[0] = (__bf16)acc0;
        pk.hb[1] = (__bf16)acc1;
        ((unsigned int*)hout)[(size_t)node * 32 + fi] = pk.u;
        float2* hp = (float2*)(hidden + (size_t)node * 64 + 2 * fi);
        float2 hv = *hp;
        hv.x = fmaf(tk, acc0, hv.x);
        hv.y = fmaf(tk, acc1, hv.y);
        *hp = hv;
    }
}

// ---------------- log_softmax in-place on d_out ----------------

__global__ __launch_bounds__(256) void lsm_kernel(float* __restrict__ io) {
    int i = blockIdx.x * 4 + (threadIdx.x >> 6);
    int j = threadIdx.x & 63;
    float v = io[(size_t)i * 64 + j];
    float m = v;
    #pragma unroll
    for (int o = 32; o > 0; o >>= 1) m = fmaxf(m, __shfl_xor(m, o));
    float ex = expf(v - m);
    float s = ex;
    #pragma unroll
    for (int o = 32; o > 0; o >>= 1) s += __shfl_xor(s, o);
    io[(size_t)i * 64 + j] = v - m - logf(s);
}

extern "C" void kernel_launch(void* const* d_in, const int* in_sizes, int n_in,
                              void* d_out, int out_size, void* d_ws, size_t ws_size,
                              hipStream_t stream) {
    const float* x    = (const float*)d_in[0];
    const int*   ei   = (const int*)d_in[1];
    const float* W1   = (const float*)d_in[2];
    const float* b1   = (const float*)d_in[3];
    const float* W2   = (const float*)d_in[4];
    const float* b2   = (const float*)d_in[5];
    const float* temp = (const float*)d_in[6];
    float* out = (float*)d_out;

    char* ws = (char*)d_ws;
    size_t off = 0;
    auto alloc = [&](size_t bytes) -> void* {
        void* p = ws + off;
        off = (off + bytes + 255) & ~(size_t)255;
        return p;
    };
    int*    deg     = (int*)alloc((size_t)N_NODES * 4);
    float*  dinv    = (float*)alloc((size_t)N_NODES * 4);
    int*    row_ptr = (int*)alloc((size_t)(N_NODES + 1) * 4);
    int*    cursor  = (int*)alloc((size_t)N_NODES * 4);
    int*    partial = (int*)alloc((size_t)SCAN_B * 4);
    int*    colb    = (int*)alloc((size_t)(N_EDGES + N_NODES) * 4);
    float*  wgtb    = (float*)alloc((size_t)(N_EDGES + N_NODES) * 4);
    __bf16* h0      = (__bf16*)alloc((size_t)N_NODES * NCLASS * 2);
    __bf16* h1      = (__bf16*)alloc((size_t)N_NODES * NCLASS * 2);
    __bf16* w1t     = (__bf16*)alloc((size_t)NFEAT * NHID * 2);
    __bf16* w2t     = (__bf16*)alloc((size_t)NHID * NCLASS * 2);

    zero_deg_kernel<<<(N_NODES + 255) / 256, 256, 0, stream>>>(deg);
    deg_kernel<<<(N_EDGES + 255) / 256, 256, 0, stream>>>(ei, deg);
    dinv_kernel<<<(N_NODES + 255) / 256, 256, 0, stream>>>(deg, dinv);
    scan1_kernel<<<SCAN_B, 256, 0, stream>>>(deg, partial);
    scan2_kernel<<<1, 512, 0, stream>>>(partial);
    scan3_kernel<<<SCAN_B, 256, 0, stream>>>(deg, partial, row_ptr, cursor);
    fill_kernel<<<(N_EDGES + N_NODES + 255) / 256, 256, 0, stream>>>(ei, dinv, cursor, colb, wgtb);
    wprep_kernel<<<(NFEAT * NHID + NHID * NCLASS + 255) / 256, 256, 0, stream>>>(W1, W2, w1t, w2t);

    mlp_kernel<<<(N_NODES + MT - 1) / MT, 256, 0, stream>>>(x, w1t, b1, w2t, b2, temp, h0, out);

    __bf16* cur = h0;
    __bf16* nxt = h1;
    for (int k = 0; k < KHOPS; ++k) {
        prop_kernel<<<N_NODES / 4, 256, 0, stream>>>(cur, nxt, out, row_ptr, colb, wgtb, temp, k + 1);
        __bf16* tswap = cur; cur = nxt; nxt = tswap;
    }

    lsm_kernel<<<N_NODES / 4, 256, 0, stream>>>(out);
}

// Round 4
// 1340.184 us; speedup vs baseline: 1.9189x; 1.1065x over previous
//
#include <hip/hip_runtime.h>

#define N_NODES 100000
#define N_EDGES 3200000
#define NFEAT 512
#define NHID 256
#define NCLASS 64
#define KHOPS 10
#define SCAN_B 391   // ceil(N_NODES/256)

typedef __bf16 bf16x8 __attribute__((ext_vector_type(8)));
typedef __bf16 bf16x4 __attribute__((ext_vector_type(4)));
typedef float f32x4 __attribute__((ext_vector_type(4)));

// ---------------- preprocessing: degrees, dinv, CSR ----------------

__global__ __launch_bounds__(256) void zero_deg_kernel(int* __restrict__ deg) {
    int i = blockIdx.x * 256 + threadIdx.x;
    if (i < N_NODES) deg[i] = 0;
}

__global__ __launch_bounds__(256) void deg_kernel(const int* __restrict__ ei, int* __restrict__ deg) {
    int e = blockIdx.x * 256 + threadIdx.x;
    if (e < N_EDGES) atomicAdd(&deg[ei[N_EDGES + e]], 1);
}

__global__ __launch_bounds__(256) void dinv_kernel(const int* __restrict__ deg, float* __restrict__ dinv) {
    int i = blockIdx.x * 256 + threadIdx.x;
    if (i < N_NODES) dinv[i] = rsqrtf((float)(deg[i] + 1)); // +1 self-loop
}

// ---- hierarchical scan of (deg[i]+1): partial sums -> scan partials -> local scan ----

__global__ __launch_bounds__(256) void scan1_kernel(const int* __restrict__ deg, int* __restrict__ partial) {
    __shared__ int red[256];
    int t = threadIdx.x;
    int i = blockIdx.x * 256 + t;
    red[t] = (i < N_NODES) ? deg[i] + 1 : 0;
    __syncthreads();
    for (int off = 128; off > 0; off >>= 1) {
        if (t < off) red[t] += red[t + off];
        __syncthreads();
    }
    if (t == 0) partial[blockIdx.x] = red[0];
}

__global__ __launch_bounds__(512) void scan2_kernel(int* __restrict__ partial) {
    __shared__ int s[512];
    int t = threadIdx.x;
    int v = (t < SCAN_B) ? partial[t] : 0;
    s[t] = v;
    __syncthreads();
    for (int off = 1; off < 512; off <<= 1) {
        int add = (t >= off) ? s[t - off] : 0;
        __syncthreads();
        s[t] += add;
        __syncthreads();
    }
    if (t < SCAN_B) partial[t] = s[t] - v; // exclusive
}

__global__ __launch_bounds__(256) void scan3_kernel(const int* __restrict__ deg,
                                                    const int* __restrict__ partial,
                                                    int* __restrict__ row_ptr,
                                                    int* __restrict__ cursor) {
    __shared__ int s[256];
    int t = threadIdx.x;
    int i = blockIdx.x * 256 + t;
    int v = (i < N_NODES) ? deg[i] + 1 : 0;
    s[t] = v;
    __syncthreads();
    for (int off = 1; off < 256; off <<= 1) {
        int add = (t >= off) ? s[t - off] : 0;
        __syncthreads();
        s[t] += add;
        __syncthreads();
    }
    int excl = s[t] - v + partial[blockIdx.x];
    if (i < N_NODES) {
        row_ptr[i] = excl;
        cursor[i] = excl;
        if (i == N_NODES - 1) row_ptr[N_NODES] = excl + v;
    }
}

// packed edge: {src, weight-as-int} -> single 8B scattered store
__global__ __launch_bounds__(256) void fill_kernel(const int* __restrict__ ei,
                                                   const float* __restrict__ dinv,
                                                   int* __restrict__ cursor,
                                                   int2* __restrict__ epk) {
    int e = blockIdx.x * 256 + threadIdx.x;
    if (e < N_EDGES) {
        int s = ei[e], d = ei[N_EDGES + e];
        int p = atomicAdd(&cursor[d], 1);
        epk[p] = make_int2(s, __float_as_int(dinv[s] * dinv[d]));
    } else if (e < N_EDGES + N_NODES) {
        int i = e - N_EDGES;
        int p = atomicAdd(&cursor[i], 1);
        float di = dinv[i];
        epk[p] = make_int2(i, __float_as_int(di * di)); // self-loop
    }
}

// ---------------- weight prep: W1^T, W2^T in bf16 ----------------

__global__ __launch_bounds__(256) void wprep_kernel(const float* __restrict__ W1,
                                                    const float* __restrict__ W2,
                                                    __bf16* __restrict__ w1t,
                                                    __bf16* __restrict__ w2t) {
    int i = blockIdx.x * 256 + threadIdx.x;
    if (i < NFEAT * NHID) {
        int n = i >> 9, k = i & 511;           // w1t[n][k], k<512
        w1t[i] = (__bf16)W1[k * NHID + n];
    } else {
        int j = i - NFEAT * NHID;
        if (j < NHID * NCLASS) {
            int n = j >> 8, k = j & 255;       // w2t[n][k], k<256
            w2t[j] = (__bf16)W2[k * NCLASS + n];
        }
    }
}

// ---------------- fused MLP via bf16 MFMA ----------------

#define MT 64
#define KC 64
#define XP 72
#define WP 72
#define HP 264

__global__ __launch_bounds__(256) void mlp_kernel(const float* __restrict__ x,
                                                  const __bf16* __restrict__ w1t,
                                                  const float* __restrict__ b1,
                                                  const __bf16* __restrict__ w2t,
                                                  const float* __restrict__ b2,
                                                  const float* __restrict__ temp,
                                                  __bf16* __restrict__ h,
                                                  float* __restrict__ hidden) {
    __shared__ char smem[46080] __attribute__((aligned(16)));
    __bf16* xs  = (__bf16*)smem;             // 64*72*2  = 9216 B
    __bf16* wt  = (__bf16*)(smem + 9216);    // 256*72*2 = 36864 B
    __bf16* h1s = (__bf16*)smem;             // 64*264*2 = 33792 B (after barrier)

    int t = threadIdx.x;
    int wv = t >> 6, lane = t & 63;
    int lrow = lane & 15;
    int quad = lane >> 4;
    int row0 = blockIdx.x * MT;
    int n0 = wv * 64;

    f32x4 acc[4][4] = {};
    for (int kc = 0; kc < NFEAT; kc += KC) {
        __syncthreads();
        for (int i = t; i < MT * 16; i += 256) {
            int r = i >> 4, c4 = i & 15;
            int row = row0 + r; if (row >= N_NODES) row = N_NODES - 1;
            float4 v = *(const float4*)&x[(size_t)row * NFEAT + kc + c4 * 4];
            bf16x4 o = { (__bf16)v.x, (__bf16)v.y, (__bf16)v.z, (__bf16)v.w };
            *(bf16x4*)&xs[r * XP + c4 * 4] = o;
        }
        for (int i = t; i < 256 * 8; i += 256) {
            int n = i >> 3, c8 = i & 7;
            bf16x8 v = *(const bf16x8*)&w1t[(size_t)n * NFEAT + kc + c8 * 8];
            *(bf16x8*)&wt[n * WP + c8 * 8] = v;
        }
        __syncthreads();
        #pragma unroll
        for (int ks = 0; ks < 2; ++ks) {
            int kof = ks * 32 + quad * 8;
            bf16x8 a[4], b[4];
            #pragma unroll
            for (int mt = 0; mt < 4; ++mt)
                a[mt] = *(const bf16x8*)&xs[(mt * 16 + lrow) * XP + kof];
            #pragma unroll
            for (int nt = 0; nt < 4; ++nt)
                b[nt] = *(const bf16x8*)&wt[(n0 + nt * 16 + lrow) * WP + kof];
            #pragma unroll
            for (int mt = 0; mt < 4; ++mt)
                #pragma unroll
                for (int nt = 0; nt < 4; ++nt)
                    acc[mt][nt] = __builtin_amdgcn_mfma_f32_16x16x32_bf16(a[mt], b[nt], acc[mt][nt], 0, 0, 0);
        }
    }
    __syncthreads();
    #pragma unroll
    for (int nt = 0; nt < 4; ++nt) {
        int coln = n0 + nt * 16 + lrow;
        float bb = b1[coln];
        #pragma unroll
        for (int mt = 0; mt < 4; ++mt) {
            int rbase = mt * 16 + quad * 4;
            #pragma unroll
            for (int r = 0; r < 4; ++r) {
                float v = acc[mt][nt][r] + bb;
                h1s[(rbase + r) * HP + coln] = (__bf16)fmaxf(v, 0.f);
            }
        }
    }
    __syncthreads();
    f32x4 acc2[4] = {};
    #pragma unroll
    for (int ks = 0; ks < 8; ++ks) {
        int kof = ks * 32 + quad * 8;
        bf16x8 a2 = *(const bf16x8*)&h1s[(wv * 16 + lrow) * HP + kof];
        #pragma unroll
        for (int nt = 0; nt < 4; ++nt) {
            bf16x8 bv = *(const bf16x8*)&w2t[(size_t)(nt * 16 + lrow) * NHID + kof];
            acc2[nt] = __builtin_amdgcn_mfma_f32_16x16x32_bf16(a2, bv, acc2[nt], 0, 0, 0);
        }
    }
    float t0 = temp[0];
    #pragma unroll
    for (int nt = 0; nt < 4; ++nt) {
        int coln = nt * 16 + lrow;
        float bb = b2[coln];
        #pragma unroll
        for (int r = 0; r < 4; ++r) {
            int row = row0 + wv * 16 + quad * 4 + r;
            if (row < N_NODES) {
                float v = acc2[nt][r] + bb;
                size_t idx = (size_t)row * NCLASS + coln;
                h[idx] = (__bf16)v;
                hidden[idx] = t0 * v;
            }
        }
    }
}

// ---------------- propagation: wave per dst node, 8 lanes/edge, dwordx4 gathers ----------------
// lane = 8*oct + fi8: octet handles edge (base+oct), lane loads 16B (8 bf16 feats) of that
// edge's source row; butterfly shfl_xor(8/16/32) sums octets; lanes 0-7 write.

__global__ __launch_bounds__(256) void prop_kernel(const __bf16* __restrict__ hin,
                                                   __bf16* __restrict__ hout,
                                                   float* __restrict__ hidden,
                                                   const int* __restrict__ row_ptr,
                                                   const int2* __restrict__ epk,
                                                   const float* __restrict__ temp,
                                                   int ktap) {
    int node = blockIdx.x * 4 + (threadIdx.x >> 6);
    int lane = threadIdx.x & 63;
    int oct = lane >> 3, fi8 = lane & 7;
    int beg = row_ptr[node], end = row_ptr[node + 1];
    const uint4* hrow = (const uint4*)hin; // node stride 8 uint4s (128B)
    float acc[8] = {};
    int nit = (end - beg + 7) >> 3;
    #pragma unroll 4
    for (int it = 0; it < nit; ++it) {
        int e = beg + it * 8 + oct;
        int ec = min(e, end - 1);       // clamp to a valid slot (branch-free tail)
        int2 ed = epk[ec];
        float w = (e < end) ? __int_as_float(ed.y) : 0.f;
        uint4 v = hrow[(size_t)ed.x * 8 + fi8];
        unsigned vv;
        vv = v.x;
        acc[0] = fmaf(w, __int_as_float(vv << 16), acc[0]);
        acc[1] = fmaf(w, __int_as_float(vv & 0xffff0000u), acc[1]);
        vv = v.y;
        acc[2] = fmaf(w, __int_as_float(vv << 16), acc[2]);
        acc[3] = fmaf(w, __int_as_float(vv & 0xffff0000u), acc[3]);
        vv = v.z;
        acc[4] = fmaf(w, __int_as_float(vv << 16), acc[4]);
        acc[5] = fmaf(w, __int_as_float(vv & 0xffff0000u), acc[5]);
        vv = v.w;
        acc[6] = fmaf(w, __int_as_float(vv << 16), acc[6]);
        acc[7] = fmaf(w, __int_as_float(vv & 0xffff0000u), acc[7]);
    }
    #pragma unroll
    for (int j = 0; j < 8; ++j) {
        acc[j] += __shfl_xor(acc[j], 8);
        acc[j] += __shfl_xor(acc[j], 16);
        acc[j] += __shfl_xor(acc[j], 32);
    }
    float tk = temp[ktap];
    if (oct == 0) {
        union { __bf16 b[8]; uint4 u; } pk;
        #pragma unroll
        for (int j = 0; j < 8; ++j) pk.b[j] = (__bf16)acc[j];
        ((uint4*)hout)[(size_t)node * 8 + fi8] = pk.u;
        float4* hp = (float4*)(hidden + (size_t)node * 64 + fi8 * 8);
        float4 a = hp[0], b = hp[1];
        a.x = fmaf(tk, acc[0], a.x); a.y = fmaf(tk, acc[1], a.y);
        a.z = fmaf(tk, acc[2], a.z); a.w = fmaf(tk, acc[3], a.w);
        b.x = fmaf(tk, acc[4], b.x); b.y = fmaf(tk, acc[5], b.y);
        b.z = fmaf(tk, acc[6], b.z); b.w = fmaf(tk, acc[7], b.w);
        hp[0] = a; hp[1] = b;
    }
}

// ---------------- log_softmax in-place on d_out ----------------

__global__ __launch_bounds__(256) void lsm_kernel(float* __restrict__ io) {
    int i = blockIdx.x * 4 + (threadIdx.x >> 6);
    int j = threadIdx.x & 63;
    float v = io[(size_t)i * 64 + j];
    float m = v;
    #pragma unroll
    for (int o = 32; o > 0; o >>= 1) m = fmaxf(m, __shfl_xor(m, o));
    float ex = expf(v - m);
    float s = ex;
    #pragma unroll
    for (int o = 32; o > 0; o >>= 1) s += __shfl_xor(s, o);
    io[(size_t)i * 64 + j] = v - m - logf(s);
}

extern "C" void kernel_launch(void* const* d_in, const int* in_sizes, int n_in,
                              void* d_out, int out_size, void* d_ws, size_t ws_size,
                              hipStream_t stream) {
    const float* x    = (const float*)d_in[0];
    const int*   ei   = (const int*)d_in[1];
    const float* W1   = (const float*)d_in[2];
    const float* b1   = (const float*)d_in[3];
    const float* W2   = (const float*)d_in[4];
    const float* b2   = (const float*)d_in[5];
    const float* temp = (const float*)d_in[6];
    float* out = (float*)d_out;

    char* ws = (char*)d_ws;
    size_t off = 0;
    auto alloc = [&](size_t bytes) -> void* {
        void* p = ws + off;
        off = (off + bytes + 255) & ~(size_t)255;
        return p;
    };
    int*    deg     = (int*)alloc((size_t)N_NODES * 4);
    float*  dinv    = (float*)alloc((size_t)N_NODES * 4);
    int*    row_ptr = (int*)alloc((size_t)(N_NODES + 1) * 4);
    int*    cursor  = (int*)alloc((size_t)N_NODES * 4);
    int*    partial = (int*)alloc((size_t)SCAN_B * 4);
    int2*   epk     = (int2*)alloc((size_t)(N_EDGES + N_NODES) * 8);
    __bf16* h0      = (__bf16*)alloc((size_t)N_NODES * NCLASS * 2);
    __bf16* h1      = (__bf16*)alloc((size_t)N_NODES * NCLASS * 2);
    __bf16* w1t     = (__bf16*)alloc((size_t)NFEAT * NHID * 2);
    __bf16* w2t     = (__bf16*)alloc((size_t)NHID * NCLASS * 2);

    zero_deg_kernel<<<(N_NODES + 255) / 256, 256, 0, stream>>>(deg);
    deg_kernel<<<(N_EDGES + 255) / 256, 256, 0, stream>>>(ei, deg);
    dinv_kernel<<<(N_NODES + 255) / 256, 256, 0, stream>>>(deg, dinv);
    scan1_kernel<<<SCAN_B, 256, 0, stream>>>(deg, partial);
    scan2_kernel<<<1, 512, 0, stream>>>(partial);
    scan3_kernel<<<SCAN_B, 256, 0, stream>>>(deg, partial, row_ptr, cursor);
    fill_kernel<<<(N_EDGES + N_NODES + 255) / 256, 256, 0, stream>>>(ei, dinv, cursor, epk);
    wprep_kernel<<<(NFEAT * NHID + NHID * NCLASS + 255) / 256, 256, 0, stream>>>(W1, W2, w1t, w2t);

    mlp_kernel<<<(N_NODES + MT - 1) / MT, 256, 0, stream>>>(x, w1t, b1, w2t, b2, temp, h0, out);

    __bf16* cur = h0;
    __bf16* nxt = h1;
    for (int k = 0; k < KHOPS; ++k) {
        prop_kernel<<<N_NODES / 4, 256, 0, stream>>>(cur, nxt, out, row_ptr, epk, temp, k + 1);
        __bf16* tswap = cur; cur = nxt; nxt = tswap;
    }

    lsm_kernel<<<N_NODES / 4, 256, 0, stream>>>(out);
}